// Round 1
// 987.432 us; speedup vs baseline: 1.1547x; 1.1547x over previous
//
#include <hip/hip_runtime.h>
#include <stdint.h>
#include <math.h>

#define TT 1024
#define FF 32
#define HH 64

typedef unsigned int u32;
typedef _Float16 f16;
typedef __attribute__((ext_vector_type(8))) _Float16 half8;  // 8 fp16 = 4 VGPRs (MFMA A/B frag)
typedef __attribute__((ext_vector_type(4))) float v4f;       // MFMA C/D frag

// hardware-exp2/rcp nonlinearities (v_exp_f32 + v_rcp_f32, ~1e-6 abs err,
// saturate correctly at +-inf: sig(-inf)=rcp(inf)=0, tanh(-inf)=2*rcp(inf)-1=-1)
__device__ __forceinline__ float fsig(float x) {
    return __builtin_amdgcn_rcpf(1.f + __builtin_amdgcn_exp2f(-1.44269504088896341f * x));
}
__device__ __forceinline__ float ftanh(float x) {
    return 2.f * __builtin_amdgcn_rcpf(1.f + __builtin_amdgcn_exp2f(-2.88539008177792681f * x)) - 1.f;
}

// load 8 consecutive fp32 -> fp16 octet (RNE), for A-fragment prep
__device__ __forceinline__ half8 ld8h(const float* p) {
    float4 a = *(const float4*)p, b = *(const float4*)(p + 4);
    half8 r;
    r[0] = (f16)a.x; r[1] = (f16)a.y; r[2] = (f16)a.z; r[3] = (f16)a.w;
    r[4] = (f16)b.x; r[5] = (f16)b.y; r[6] = (f16)b.z; r[7] = (f16)b.w;
    return r;
}

// Structure change vs previous round: ONE barrier per step.
//  - gpart hand-off is wave-local: wave w owns tiles w*6..w*6+5 == gate slots
//    [w*24, w*24+24). Lane l<24 of wave w consumes slot g=w*24+l, so the
//    write->read only needs s_waitcnt lgkmcnt(0) (inline asm + "memory"), not
//    a workgroup barrier. Phase-2 is now spread evenly over all 4 waves.
//  - Bst is double-buffered on step parity: reads from buf p=tt&1, h/x writes
//    to buf p^1, removing the WAR race the old mid-step barrier protected.
//  - x chunk prefetch: global loads issued at top of step, LDS write deferred
//    to just before the barrier (latency hides under MFMA + nonlinearities).
//  - sigmoid/tanh via v_exp_f32/v_rcp_f32 instead of libm expf/tanhf.

__global__ __launch_bounds__(256, 2)
void lstm_ae_mfma(const float* __restrict__ x,
                  const float* __restrict__ ewih, const float* __restrict__ ewhh,
                  const float* __restrict__ ebih, const float* __restrict__ ebhh,
                  const float* __restrict__ dwih, const float* __restrict__ dwhh,
                  const float* __restrict__ dbih, const float* __restrict__ dbhh,
                  float* __restrict__ out)
{
    const int b = blockIdx.x;
    const int t = threadIdx.x;
    const int w = t >> 6;        // wave 0..3
    const int l = t & 63;
    const int q = l >> 4;        // quad: A/B k-group, D row-group
    const int n = l & 15;        // A row-in-tile / B+D column

    __shared__ __align__(16) f16 Bst[2][16][104];    // B operand, DOUBLE-buffered
    __shared__ __align__(16) float xst[2][2048];     // x 64-step chunks, fp32, dbuf
    __shared__ __align__(16) float gpart[2][96 * 4]; // [hi/lo][slot*4+gate], wave-local regions

    // ---- persistent A fragments (fp32 -> fp16): lane holds A[m=n][k=q*8+j] ----
    half8 af[6][3];
#pragma unroll
    for (int i = 0; i < 6; ++i) {
        int tile = w * 6 + i;
        if (tile < 16) {
            int r = (n & 3) * 64 + tile * 4 + (n >> 2);          // enc W row
            af[i][0] = ld8h(ewhh + r * 64 + q * 8);
            af[i][1] = ld8h(ewhh + r * 64 + 32 + q * 8);
            af[i][2] = ld8h(ewih + r * 32 + q * 8);
        } else {
            int r = (n & 3) * 32 + (tile - 16) * 4 + (n >> 2);   // dec V row
            af[i][0] = ld8h(dwih + r * 64 + q * 8);
            af[i][1] = ld8h(dwih + r * 64 + 32 + q * 8);
            af[i][2] = ld8h(dwhh + r * 32 + q * 8);
        }
    }

    // ---- reader lane (l<24 of wave w) owns slot g = w*24+l: bias + cell state ----
    const int g = w * 24 + l;    // g<64: enc unit g ; 64<=g<96: dec unit g-64
    float b0 = 0.f, b1 = 0.f, b2 = 0.f, b3 = 0.f, c_st = 0.f;
    if (l < 24) {
        if (g < 64) {
            b0 = ebih[g]       + ebhh[g];
            b1 = ebih[64 + g]  + ebhh[64 + g];
            b2 = ebih[128 + g] + ebhh[128 + g];
            b3 = ebih[192 + g] + ebhh[192 + g];
        } else {
            int u = g - 64;
            b0 = dbih[u]      + dbhh[u];
            b1 = dbih[32 + u] + dbhh[32 + u];
            b2 = dbih[64 + u] + dbhh[64 + u];
            b3 = dbih[96 + u] + dbhh[96 + u];
        }
    }

    // ---- prologue: zero both Bst buffers, stage x chunk 0, x[0] into buf0 col0 ----
    { u32* bz = (u32*)&Bst[0][0][0]; for (int i2 = t; i2 < 2 * 16 * 104 / 2; i2 += 256) bz[i2] = 0u; }
    const float* xb = x + (size_t)b * TT * FF;
    *(float4*)&xst[0][t * 8]     = *(const float4*)(xb + t * 8);
    *(float4*)&xst[0][t * 8 + 4] = *(const float4*)(xb + t * 8 + 4);
    __syncthreads();
    if (t >= 96 && t < 128) Bst[0][0][64 + (t - 96)] = (f16)xst[0][t - 96];
    __syncthreads();

    for (int tt = 0; tt <= TT; ++tt) {
        const int p = tt & 1;

        // x chunk prefetch: issue loads now, write LDS just before the barrier
        float4 px0, px1;
        const int cn = (tt >> 6) + 1;
        const bool pf = ((tt & 63) == 0) && (cn < 16);
        if (pf) {
            px0 = *(const float4*)(xb + cn * 2048 + t * 8);
            px1 = *(const float4*)(xb + cn * 2048 + t * 8 + 4);
        }

        // ---- B fragments + 18 MFMAs/wave (read buf p) ----
        const f16* Bp = &Bst[p][0][0];
        half8 bf0 = *(const half8*)(Bp + n * 104 + q * 8);
        half8 bf1 = *(const half8*)(Bp + n * 104 + 32 + q * 8);
        half8 bf2 = *(const half8*)(Bp + n * 104 + 64 + q * 8);

        v4f zero = {0.f, 0.f, 0.f, 0.f};
        v4f acc[6];
#pragma unroll
        for (int i = 0; i < 6; ++i)
            acc[i] = __builtin_amdgcn_mfma_f32_16x16x32_f16(af[i][0], bf0, zero, 0, 0, 0);
#pragma unroll
        for (int i = 0; i < 6; ++i)
            acc[i] = __builtin_amdgcn_mfma_f32_16x16x32_f16(af[i][1], bf1, acc[i], 0, 0, 0);
#pragma unroll
        for (int i = 0; i < 6; ++i)
            acc[i] = __builtin_amdgcn_mfma_f32_16x16x32_f16(af[i][2], bf2, acc[i], 0, 0, 0);

        // hi/lo partials to this wave's gpart region (predicated ds_write_b128)
#pragma unroll
        for (int i = 0; i < 6; ++i) {
            int tile = w * 6 + i;
            if (tile < 16) {
                if (n < 2) *(v4f*)&gpart[n][(tile * 4 + q) * 4] = acc[i];
            } else {
                if (n == 2 || n == 3)
                    *(v4f*)&gpart[n - 2][(64 + (tile - 16) * 4 + q) * 4] = acc[i];
            }
        }

        // wave-local hand-off: drain this wave's LDS writes (NOT a workgroup barrier)
        asm volatile("s_waitcnt lgkmcnt(0)" ::: "memory");

        // ---- per-wave phase 2: 24 reader lanes, one unit each; writes go to buf p^1 ----
        if (l < 24) {
            const bool e_ = (g < 64);
            if (e_ ? (tt < TT) : (tt >= 1)) {
                v4f gh = *(const v4f*)&gpart[0][g * 4];
                v4f gl = *(const v4f*)&gpart[1][g * 4];
                float i_ = fsig(gh[0] + gl[0] + b0);
                float f_ = fsig(gh[1] + gl[1] + b1);
                float g_ = ftanh(gh[2] + gl[2] + b2);
                float o_ = fsig(gh[3] + gl[3] + b3);
                c_st = f_ * c_st + i_ * g_;
                float h = o_ * ftanh(c_st);
                f16 hi = (f16)h;
                f16 lo = (f16)(h - (float)hi);
                f16* Bw = &Bst[p ^ 1][0][0];
                if (e_) {                       // encoder unit g, step tt
                    Bw[g]           = hi;  Bw[2 * 104 + g] = hi;
                    Bw[104 + g]     = lo;  Bw[3 * 104 + g] = lo;
                } else {                        // decoder unit g-64, step tt-1
                    int u = g - 64;
                    Bw[2 * 104 + 64 + u] = hi;
                    Bw[3 * 104 + 64 + u] = lo;
                    out[(size_t)b * TT * FF + (size_t)(tt - 1) * FF + u] = h;
                }
            }
        } else if (l >= 32 && l < 40) {         // stage x for enc step tt+1 (8 lanes/wave)
            int st = tt + 1;
            if (st < TT) {
                int j = w * 8 + (l - 32);
                Bst[p ^ 1][0][64 + j] = (f16)xst[(st >> 6) & 1][(st & 63) * 32 + j];
            }
        }

        // deferred prefetch write (loads have been in flight across MFMA + phase 2)
        if (pf) {
            *(float4*)&xst[cn & 1][t * 8]     = px0;
            *(float4*)&xst[cn & 1][t * 8 + 4] = px1;
        }

        __syncthreads();   // the ONLY barrier per step
    }
}

extern "C" void kernel_launch(void* const* d_in, const int* in_sizes, int n_in,
                              void* d_out, int out_size, void* d_ws, size_t ws_size,
                              hipStream_t stream) {
    (void)in_sizes; (void)n_in; (void)out_size; (void)d_ws; (void)ws_size;
    lstm_ae_mfma<<<512, 256, 0, stream>>>((const float*)d_in[0],
                                          (const float*)d_in[1], (const float*)d_in[2],
                                          (const float*)d_in[3], (const float*)d_in[4],
                                          (const float*)d_in[5], (const float*)d_in[6],
                                          (const float*)d_in[7], (const float*)d_in[8],
                                          (float*)d_out);
}

// Round 2
// 740.833 us; speedup vs baseline: 1.5391x; 1.3329x over previous
//
#include <hip/hip_runtime.h>
#include <stdint.h>
#include <math.h>

#define TT 1024
#define FF 32
#define HH 64

typedef unsigned int u32;
typedef _Float16 f16;
typedef __attribute__((ext_vector_type(8))) _Float16 half8;  // 8 fp16 = 4 VGPRs (MFMA A/B frag)
typedef __attribute__((ext_vector_type(4))) float v4f;       // MFMA C/D frag

// hardware-exp2/rcp nonlinearities (v_exp_f32 + v_rcp_f32, ~1e-6 abs err,
// saturate correctly at +-inf)
__device__ __forceinline__ float fsig(float x) {
    return __builtin_amdgcn_rcpf(1.f + __builtin_amdgcn_exp2f(-1.44269504088896341f * x));
}
__device__ __forceinline__ float ftanh(float x) {
    return 2.f * __builtin_amdgcn_rcpf(1.f + __builtin_amdgcn_exp2f(-2.88539008177792681f * x)) - 1.f;
}

// load 8 consecutive fp32 -> fp16 octet (RNE), for A-fragment prep
__device__ __forceinline__ half8 ld8h(const float* p) {
    float4 a = *(const float4*)p, b = *(const float4*)(p + 4);
    half8 r;
    r[0] = (f16)a.x; r[1] = (f16)a.y; r[2] = (f16)a.z; r[3] = (f16)a.w;
    r[4] = (f16)b.x; r[5] = (f16)b.y; r[6] = (f16)b.z; r[7] = (f16)b.w;
    return r;
}

// Round-2 structure: NO gpart LDS round-trip.
//  - B operand collapsed to 2 physical columns (hi/lo), read replicated via
//    col = n&1 (8 lanes/address -> broadcast, conflict-free with 160-f16 col
//    stride = 80 dwords = 16 mod 32). D cols n>=2 replicate n&1 -> garbage-free.
//  - Unified K layout per column: [h_enc(0..63) | x(64..95) | h_dec(96..127)].
//    enc A-tiles consume k0..95 (bf0,bf1,bf2); dec A-tiles k0..63 + k96..127
//    (bf0,bf1,bf3). col1's x-region stays zero forever (zeroed at init).
//  - hi+lo gate reduce = DPP quad_perm[1,0,3,2] + v_add (lane n <-> n^1), pure
//    VALU. Lane pair (2s, 2s+1), s<6, owns tile w*6+s: both lanes compute the
//    unit update redundantly (identical inputs); even lane writes hi to col0,
//    odd lane writes lo to col1 -- one ds_write_b16 each.
//  - Lanes n=12,13 stage x for step tt+1 (2 f16 per wave-lane-group).
//  - Bst double-buffered on step parity; ONE barrier per step.
//  - x chunk prefetch: global loads issued at top of step, LDS write deferred.

__global__ __launch_bounds__(256, 2)
void lstm_ae_mfma(const float* __restrict__ x,
                  const float* __restrict__ ewih, const float* __restrict__ ewhh,
                  const float* __restrict__ ebih, const float* __restrict__ ebhh,
                  const float* __restrict__ dwih, const float* __restrict__ dwhh,
                  const float* __restrict__ dbih, const float* __restrict__ dbhh,
                  float* __restrict__ out)
{
    const int b = blockIdx.x;
    const int t = threadIdx.x;
    const int w = t >> 6;        // wave 0..3
    const int l = t & 63;
    const int q = l >> 4;        // quad: A/B k-group, D row-group
    const int n = l & 15;        // A row-in-tile / B+D column

    __shared__ __align__(16) f16 Bst[2][2][160];     // [buf][col hi/lo][K(128)+pad]
    __shared__ __align__(16) float xst[2][2048];     // x 64-step chunks, fp32, dbuf

    // ---- persistent A fragments (fp32 -> fp16): lane holds A[m=n][k=q*8+j] ----
    half8 af[6][3];
#pragma unroll
    for (int i = 0; i < 6; ++i) {
        int tile = w * 6 + i;
        if (tile < 16) {
            int r = (n & 3) * 64 + tile * 4 + (n >> 2);          // enc W row
            af[i][0] = ld8h(ewhh + r * 64 + q * 8);              // pairs bf0 (h_enc hi/lo 0..31)
            af[i][1] = ld8h(ewhh + r * 64 + 32 + q * 8);         // pairs bf1 (h_enc 32..63)
            af[i][2] = ld8h(ewih + r * 32 + q * 8);              // pairs bf2 (x)
        } else {
            int r = (n & 3) * 32 + (tile - 16) * 4 + (n >> 2);   // dec V row
            af[i][0] = ld8h(dwih + r * 64 + q * 8);              // pairs bf0 (h_enc 0..31)
            af[i][1] = ld8h(dwih + r * 64 + 32 + q * 8);         // pairs bf1 (h_enc 32..63)
            af[i][2] = ld8h(dwhh + r * 32 + q * 8);              // pairs bf3 (h_dec)
        }
    }

    // ---- lane-pair roles: pair s=n>>1 (<6) owns tile w*6+s; even=hi, odd=lo ----
    const int sel = n >> 1;                          // 0..7
    const bool act = (n < 12);                       // 6 pairs active
    const int tile_s = w * 6 + (sel < 6 ? sel : 0);  // clamped for inactive lanes
    const bool is_enc = (tile_s < 16);
    const int u = is_enc ? (tile_s * 4 + q) : ((tile_s - 16) * 4 + q);

    float b0 = 0.f, b1 = 0.f, b2 = 0.f, b3 = 0.f, c_st = 0.f;
    if (act) {
        if (is_enc) {
            b0 = ebih[u]       + ebhh[u];
            b1 = ebih[64 + u]  + ebhh[64 + u];
            b2 = ebih[128 + u] + ebhh[128 + u];
            b3 = ebih[192 + u] + ebhh[192 + u];
        } else {
            b0 = dbih[u]      + dbhh[u];
            b1 = dbih[32 + u] + dbhh[32 + u];
            b2 = dbih[64 + u] + dbhh[64 + u];
            b3 = dbih[96 + u] + dbhh[96 + u];
        }
    }

    // ---- prologue: zero both Bst buffers, stage x chunk 0, x[0] into buf0 ----
    { u32* bz = (u32*)&Bst[0][0][0]; for (int i2 = t; i2 < 2 * 2 * 160 / 2; i2 += 256) bz[i2] = 0u; }
    const float* xb = x + (size_t)b * TT * FF;
    *(float4*)&xst[0][t * 8]     = *(const float4*)(xb + t * 8);
    *(float4*)&xst[0][t * 8 + 4] = *(const float4*)(xb + t * 8 + 4);
    __syncthreads();
    if (t >= 96 && t < 128) Bst[0][0][64 + (t - 96)] = (f16)xst[0][t - 96];
    __syncthreads();

    for (int tt = 0; tt <= TT; ++tt) {
        const int p = tt & 1;

        // x chunk prefetch: issue loads now, write LDS just before the barrier
        float4 px0, px1;
        const int cn = (tt >> 6) + 1;
        const bool pf = ((tt & 63) == 0) && (cn < 16);
        if (pf) {
            px0 = *(const float4*)(xb + cn * 2048 + t * 8);
            px1 = *(const float4*)(xb + cn * 2048 + t * 8 + 4);
        }

        // ---- B fragments (col = n&1 replicated, broadcast reads) ----
        const f16* Bp = &Bst[p][0][0];
        const int cb = (n & 1) * 160 + q * 8;
        half8 bf0 = *(const half8*)(Bp + cb);
        half8 bf1 = *(const half8*)(Bp + cb + 32);
        half8 bf2 = *(const half8*)(Bp + cb + 64);
        half8 bf3 = *(const half8*)(Bp + cb + 96);

        v4f zero = {0.f, 0.f, 0.f, 0.f};
        v4f acc[6];
#pragma unroll
        for (int i = 0; i < 6; ++i) {
            const int tile = w * 6 + i;                       // wave-uniform branch
            acc[i] = __builtin_amdgcn_mfma_f32_16x16x32_f16(af[i][2], (tile < 16) ? bf2 : bf3,
                                                            zero, 0, 0, 0);
        }
#pragma unroll
        for (int i = 0; i < 6; ++i)
            acc[i] = __builtin_amdgcn_mfma_f32_16x16x32_f16(af[i][0], bf0, acc[i], 0, 0, 0);
#pragma unroll
        for (int i = 0; i < 6; ++i)
            acc[i] = __builtin_amdgcn_mfma_f32_16x16x32_f16(af[i][1], bf1, acc[i], 0, 0, 0);

        // ---- select this pair's tile (cndmask chain, static indices) ----
        v4f u_ = acc[0];
#pragma unroll
        for (int i = 1; i < 6; ++i) if (sel == i) u_ = acc[i];

        // ---- hi+lo reduce: lane n <-> n^1 via DPP quad_perm [1,0,3,2] ----
        v4f s_;
#pragma unroll
        for (int e = 0; e < 4; ++e) {
            int tmp = __builtin_amdgcn_update_dpp(0, __float_as_int(u_[e]), 0xB1, 0xF, 0xF, true);
            s_[e] = u_[e] + __int_as_float(tmp);
        }

        // ---- unit update (both lanes of pair, redundant) + h write to buf p^1 ----
        f16* Bw = &Bst[p ^ 1][0][0];
        if (act && (is_enc ? (tt < TT) : (tt >= 1))) {
            float i_ = fsig(s_[0] + b0);
            float f_ = fsig(s_[1] + b1);
            float g_ = ftanh(s_[2] + b2);
            float o_ = fsig(s_[3] + b3);
            c_st = f_ * c_st + i_ * g_;
            float h = o_ * ftanh(c_st);
            f16 hi = (f16)h;
            f16 lo = (f16)(h - (float)hi);
            const int kk = is_enc ? u : (96 + u);
            Bw[(n & 1) * 160 + kk] = (n & 1) ? lo : hi;
            if (!is_enc && !(n & 1))
                out[(size_t)b * TT * FF + (size_t)(tt - 1) * FF + u] = h;
        } else if (n == 12 || n == 13) {        // stage x for enc step tt+1
            int st = tt + 1;
            if (st < TT) {
                int j = w * 8 + q * 2 + (n - 12);
                Bw[64 + j] = (f16)xst[(st >> 6) & 1][(st & 63) * 32 + j];
            }
        }

        // deferred x-chunk prefetch write (loads in flight across MFMA + update)
        if (pf) {
            *(float4*)&xst[cn & 1][t * 8]     = px0;
            *(float4*)&xst[cn & 1][t * 8 + 4] = px1;
        }

        __syncthreads();   // the only barrier per step
    }
}

extern "C" void kernel_launch(void* const* d_in, const int* in_sizes, int n_in,
                              void* d_out, int out_size, void* d_ws, size_t ws_size,
                              hipStream_t stream) {
    (void)in_sizes; (void)n_in; (void)out_size; (void)d_ws; (void)ws_size;
    lstm_ae_mfma<<<512, 256, 0, stream>>>((const float*)d_in[0],
                                          (const float*)d_in[1], (const float*)d_in[2],
                                          (const float*)d_in[3], (const float*)d_in[4],
                                          (const float*)d_in[5], (const float*)d_in[6],
                                          (const float*)d_in[7], (const float*)d_in[8],
                                          (float*)d_out);
}